// Round 5
// baseline (484.804 us; speedup 1.0000x reference)
//
#include <hip/hip_runtime.h>

typedef _Float16 f16x8 __attribute__((ext_vector_type(8)));
typedef float f32x4 __attribute__((ext_vector_type(4)));

#define N_IMP 300000
#define N_ATOMS 100000
#define NT (N_IMP / 16)        // 18750 tiles of 16 rows
#define PERS_BLOCKS 768        // 3 blocks/CU * 256 CUs
#define WSTRIDE (PERS_BLOCKS * 4)

__device__ __forceinline__ unsigned short f2h(float f) {
  _Float16 h = (_Float16)f;  // v_cvt_f16_f32, RNE
  return __builtin_bit_cast(unsigned short, h);
}
__device__ __forceinline__ unsigned int pk2(float a, float b) {
  return (unsigned int)f2h(a) | ((unsigned int)f2h(b) << 16);
}

// Packed f16 weights in d_ws (ushort units):
//  [0,16384)      Wa  [n][k]  = W1[0:128] + W1[256:384] + W1[384:512]
//  [16384,32768)  Wb  [n][k]  = 3*W1[128:256]
//  [32768,49152)  W2p [n][k]
//  [49152,65536)  W3p [n][k]
//  [65536,67584)  Wop [16][128] (cols 6..15 zero)
//  [67584,67712)  b1 as f16 (128)
//  [67712, +25.6M) uv [atom][256] f16: u = h@Wa (0:128), v = h@Wb (128:256)
#define PB1 67584
#define UV_OFF 67712
#define WS_NEED (2ull * (UV_OFF + (unsigned long long)N_ATOMS * 256))

__global__ __launch_bounds__(256) void prep_kernel(
    const float* __restrict__ W1, const float* __restrict__ W2,
    const float* __restrict__ W3, const float* __restrict__ Wo,
    const float* __restrict__ b1, unsigned short* __restrict__ P) {
  int t = blockIdx.x * 256 + threadIdx.x;  // grid 265 blocks = 67840 threads
  if (t >= UV_OFF) return;
  float v;
  if (t < 16384) {
    int n = t >> 7, k = t & 127;
    v = W1[k * 128 + n] + W1[(k + 256) * 128 + n] + W1[(k + 384) * 128 + n];
  } else if (t < 32768) {
    int i = t - 16384; int n = i >> 7, k = i & 127;
    v = 3.0f * W1[(k + 128) * 128 + n];
  } else if (t < 49152) {
    int i = t - 32768; int n = i >> 7, k = i & 127;
    v = W2[k * 128 + n];
  } else if (t < 65536) {
    int i = t - 49152; int n = i >> 7, k = i & 127;
    v = W3[k * 128 + n];
  } else if (t < PB1) {
    int i = t - 65536; int n = i >> 7, k = i & 127;
    v = (n < 6) ? Wo[k * 6 + n] : 0.0f;
  } else {
    v = b1[t - PB1];
  }
  P[t] = f2h(v);
}

// Swizzled LDS tile, row stride 256 B (G4: row-major D=128 f16 is a 16-way
// conflict on ds_read_b128 without the XOR).
__device__ __forceinline__ int swz_off(int row, int kbyte) {
  return (row * 256 + kbyte) ^ ((row & 7) << 4);
}
__device__ __forceinline__ f16x8 lds_frag(const unsigned short* buf, int row, int k0) {
  return *(const f16x8*)((const char*)buf + swz_off(row, k0 * 2));
}
__device__ __forceinline__ void lds_st1(unsigned short* buf, int row, int col, unsigned short v) {
  *(unsigned short*)((char*)buf + swz_off(row, col * 2)) = v;
}
// Wave-local LDS fence: all lanes share one PC; lgkmcnt(0) drains this wave's
// LDS ops, "memory" clobber stops hipcc moving ds ops across it.
__device__ __forceinline__ void wave_lds_fence() {
  asm volatile("s_waitcnt lgkmcnt(0)" ::: "memory");
}

// ============ atom precompute: uv = [h@Wa | h@Wb] (f16), LDS-free ============
__global__ __launch_bounds__(256, 4) void atom_gemm(
    const float* __restrict__ h, const unsigned short* __restrict__ P,
    unsigned short* __restrict__ uv) {
  const int lane = threadIdx.x & 63;
  const int wid = threadIdx.x >> 6;
  const int atom0 = blockIdx.x * 64 + wid * 16;
  if (atom0 >= N_ATOMS) return;  // N_ATOMS % 16 == 0
  const int col = lane & 15, hi = lane >> 4;

  const float4* ph = (const float4*)(h + (long)(atom0 + col) * 128);
  f16x8 bfr[4];
#pragma unroll
  for (int ks = 0; ks < 4; ++ks) {
    int k0 = ks * 32 + hi * 8;  // float index
    float4 v0 = ph[k0 / 4], v1 = ph[k0 / 4 + 1];
    f16x8 b;
    b[0] = (_Float16)v0.x; b[1] = (_Float16)v0.y; b[2] = (_Float16)v0.z; b[3] = (_Float16)v0.w;
    b[4] = (_Float16)v1.x; b[5] = (_Float16)v1.y; b[6] = (_Float16)v1.z; b[7] = (_Float16)v1.w;
    bfr[ks] = b;
  }
  f32x4 acc[16] = {};
#pragma unroll
  for (int ks = 0; ks < 4; ++ks) {
    int k0 = ks * 32 + hi * 8;
#pragma unroll
    for (int n = 0; n < 16; ++n) {
      f16x8 a = *(const f16x8*)(P + (n * 16 + col) * 128 + k0);
      acc[n] = __builtin_amdgcn_mfma_f32_16x16x32_f16(a, bfr[ks], acc[n], 0, 0, 0);
    }
  }
  unsigned short* dst = uv + (long)(atom0 + col) * 256 + hi * 4;
#pragma unroll
  for (int n = 0; n < 16; ++n) {
    uint2 w; w.x = pk2(acc[n][0], acc[n][1]); w.y = pk2(acc[n][2], acc[n][3]);
    *(uint2*)(dst + n * 16) = w;
  }
}

__device__ __forceinline__ void wave_epilogue(
    f32x4 (&acc)[8], const float* __restrict__ bias, unsigned short* Yb, int lane) {
#pragma unroll
  for (int n = 0; n < 8; ++n) {
    int col = n * 16 + (lane & 15);
    float bn = bias[col];
#pragma unroll
    for (int r = 0; r < 4; ++r) {
      float v = fmaxf(acc[n][r] + bn, 0.0f);
      lds_st1(Yb, (lane >> 4) * 4 + r, col, f2h(v));
    }
  }
}

// Persistent pipelined main kernel: each wave grid-strides over 16-row tiles.
// Pipeline: consume gathers of tile t -> immediately ISSUE gathers of tile t+1
// -> compute layers 2/3/head of t (~2k cycles) while they fly. Index loads
// prefetched 2 tiles ahead. No __syncthreads; wave-private 4 KB LDS tile.
__global__ __launch_bounds__(256, 3) void janossy4(
    const unsigned short* __restrict__ uv, const int* __restrict__ idx0,
    const int* __restrict__ idx1, const int* __restrict__ idx2,
    const int* __restrict__ idx3, const float* __restrict__ b2,
    const float* __restrict__ b3, const float* __restrict__ bo,
    const unsigned short* __restrict__ P, float* __restrict__ out) {
  __shared__ __attribute__((aligned(16))) unsigned short Y[4][16 * 128];
  const int lane = threadIdx.x & 63;
  const int wid = threadIdx.x >> 6;
  const int row = lane & 15, hi = lane >> 4;
  int w = blockIdx.x * 4 + wid;  // global wave id
  if (w >= NT) return;

  const char* uvB = (const char*)uv;
  const float bov = (row < 6) ? bo[row] : 0.0f;

  f16x8 g0[4], g1[4], g2[4], g3[4];
  int j0, j1, j2, j3;

  auto ld_idx = [&](int tt) {
    int r = tt * 16 + row;
    j0 = idx0[r]; j1 = idx1[r]; j2 = idx2[r]; j3 = idx3[r];
  };
  auto issue_g = [&](unsigned int a, unsigned int b, unsigned int c, unsigned int d) {
#pragma unroll
    for (int ks = 0; ks < 4; ++ks) {
      int off = ks * 64 + hi * 16;  // bytes within the 256B u/v segment
      g0[ks] = *(const f16x8*)(uvB + a + off);
      g1[ks] = *(const f16x8*)(uvB + b + off);
      g2[ks] = *(const f16x8*)(uvB + c + off);
      g3[ks] = *(const f16x8*)(uvB + d + off);
    }
  };

  // ---- prologue: gathers for first tile, indices for second ----
  int t = w;
  ld_idx(t);
  issue_g((unsigned int)j0 * 512, (unsigned int)j1 * 512 + 256,
          (unsigned int)j2 * 512, (unsigned int)j3 * 512);
  { int tp = (t + WSTRIDE < NT) ? t + WSTRIDE : t; ld_idx(tp); }

  for (;;) {
    const int tn = t + WSTRIDE;
    const bool hn = tn < NT;  // wave-uniform
    // next-tile offsets from prefetched indices
    unsigned int n0 = (unsigned int)j0 * 512, n1 = (unsigned int)j1 * 512 + 256;
    unsigned int n2 = (unsigned int)j2 * 512, n3 = (unsigned int)j3 * 512;

    // ---- consume gathers of t: x = relu(u0+u2+u3+v1+b1), packed f16 ----
    f16x8 x[4];
#pragma unroll
    for (int ks = 0; ks < 4; ++ks) {
      f16x8 bb = *(const f16x8*)(P + PB1 + ks * 32 + hi * 8);
      f16x8 s = g0[ks] + g1[ks] + g2[ks] + g3[ks] + bb;
      f16x8 z = {};
      x[ks] = __builtin_elementwise_max(s, z);
    }

    // ---- issue next tile's gathers + prefetch indices 2 ahead ----
    if (hn) {
      issue_g(n0, n1, n2, n3);
      int tp = (tn + WSTRIDE < NT) ? tn + WSTRIDE : tn;
      ld_idx(tp);
    }

    // ---- layer 2 (A = x from registers) ----
    f32x4 acc[8] = {};
#pragma unroll
    for (int ks = 0; ks < 4; ++ks) {
      int k0 = ks * 32 + hi * 8;
#pragma unroll
      for (int n = 0; n < 8; ++n) {
        f16x8 b = *(const f16x8*)(P + 32768 + (n * 16 + row) * 128 + k0);
        acc[n] = __builtin_amdgcn_mfma_f32_16x16x32_f16(x[ks], b, acc[n], 0, 0, 0);
      }
    }
    wave_epilogue(acc, b2, Y[wid], lane);
    wave_lds_fence();

    // ---- layer 3 ----
    f32x4 acc3[8] = {};
#pragma unroll
    for (int ks = 0; ks < 4; ++ks) {
      int k0 = ks * 32 + hi * 8;
      f16x8 a = lds_frag(Y[wid], row, k0);
#pragma unroll
      for (int n = 0; n < 8; ++n) {
        f16x8 b = *(const f16x8*)(P + 49152 + (n * 16 + row) * 128 + k0);
        acc3[n] = __builtin_amdgcn_mfma_f32_16x16x32_f16(a, b, acc3[n], 0, 0, 0);
      }
    }
    wave_lds_fence();
    wave_epilogue(acc3, b3, Y[wid], lane);
    wave_lds_fence();

    // ---- head + coalesced store (LDS bounce -> contiguous 384 B) ----
    {
      f32x4 acch = {0.f, 0.f, 0.f, 0.f};
#pragma unroll
      for (int ks = 0; ks < 4; ++ks) {
        int k0 = ks * 32 + hi * 8;
        f16x8 a = lds_frag(Y[wid], row, k0);
        f16x8 b = *(const f16x8*)(P + 65536 + row * 128 + k0);
        acch = __builtin_amdgcn_mfma_f32_16x16x32_f16(a, b, acch, 0, 0, 0);
      }
      float* Yf = (float*)Y[wid];
      if (row < 6) {
#pragma unroll
        for (int r = 0; r < 4; ++r) Yf[(hi * 4 + r) * 6 + row] = acch[r] + bov;
      }
      wave_lds_fence();
      if (lane < 48) {
        float2 v = ((const float2*)Yf)[lane];
        *(float2*)(out + (long)t * 96 + lane * 2) = v;
      }
      wave_lds_fence();
    }

    if (!hn) break;
    t = tn;
  }
}

// ===================== fallback path (R1, needs only 135 KB ws) =====================

__device__ __forceinline__ void lds_st4(unsigned short* buf, int row, int k0,
                                        float a, float b, float c, float d) {
  uint2 u; u.x = pk2(a, b); u.y = pk2(c, d);
  *(uint2*)((char*)buf + swz_off(row, k0 * 2)) = u;
}

template <bool DUAL>
__device__ __forceinline__ void mlp_layer(
    const unsigned short* A1, const unsigned short* __restrict__ B1,
    const unsigned short* A2, const unsigned short* __restrict__ B2,
    const float* __restrict__ bias, unsigned short* Obuf, int lane, int wr, int wc) {
  f32x4 acc[2][4] = {};
#pragma unroll
  for (int ks = 0; ks < 4; ++ks) {
    int k0 = ks * 32 + (lane >> 4) * 8;
    f16x8 a0 = lds_frag(A1, wr * 32 + (lane & 15), k0);
    f16x8 a1 = lds_frag(A1, wr * 32 + 16 + (lane & 15), k0);
#pragma unroll
    for (int n = 0; n < 4; ++n) {
      int col = wc * 64 + n * 16 + (lane & 15);
      f16x8 b = *(const f16x8*)(B1 + col * 128 + k0);
      acc[0][n] = __builtin_amdgcn_mfma_f32_16x16x32_f16(a0, b, acc[0][n], 0, 0, 0);
      acc[1][n] = __builtin_amdgcn_mfma_f32_16x16x32_f16(a1, b, acc[1][n], 0, 0, 0);
    }
  }
  if constexpr (DUAL) {
#pragma unroll
    for (int ks = 0; ks < 4; ++ks) {
      int k0 = ks * 32 + (lane >> 4) * 8;
      f16x8 a0 = lds_frag(A2, wr * 32 + (lane & 15), k0);
      f16x8 a1 = lds_frag(A2, wr * 32 + 16 + (lane & 15), k0);
#pragma unroll
      for (int n = 0; n < 4; ++n) {
        int col = wc * 64 + n * 16 + (lane & 15);
        f16x8 b = *(const f16x8*)(B2 + col * 128 + k0);
        acc[0][n] = __builtin_amdgcn_mfma_f32_16x16x32_f16(a0, b, acc[0][n], 0, 0, 0);
        acc[1][n] = __builtin_amdgcn_mfma_f32_16x16x32_f16(a1, b, acc[1][n], 0, 0, 0);
      }
    }
  }
#pragma unroll
  for (int n = 0; n < 4; ++n) {
    int col = wc * 64 + n * 16 + (lane & 15);
    float bn = bias[col];
#pragma unroll
    for (int m = 0; m < 2; ++m) {
#pragma unroll
      for (int r = 0; r < 4; ++r) {
        float v = fmaxf(acc[m][n][r] + bn, 0.0f);
        lds_st1(Obuf, wr * 32 + m * 16 + (lane >> 4) * 4 + r, col, f2h(v));
      }
    }
  }
}

__global__ __launch_bounds__(256) void janossy_kernel(
    const float* __restrict__ h, const int* __restrict__ idx0,
    const int* __restrict__ idx1, const int* __restrict__ idx2,
    const int* __restrict__ idx3, const float* __restrict__ b1,
    const float* __restrict__ b2, const float* __restrict__ b3,
    const float* __restrict__ bo, const unsigned short* __restrict__ P,
    float* __restrict__ out) {
  __shared__ __attribute__((aligned(16))) unsigned short sA[64 * 128];
  __shared__ __attribute__((aligned(16))) unsigned short tA[64 * 128];
  __shared__ __attribute__((aligned(16))) unsigned short xA[64 * 128];
  const int tid = threadIdx.x;
  const int lane = tid & 63;
  const int wid = tid >> 6;
  const int wr = wid & 1, wc = wid >> 1;
  const int blk = blockIdx.x;
  {
    int row = tid >> 2, q = tid & 3;
    int rg = blk * 64 + row;
    if (rg < N_IMP) {
      const float4* p0 = (const float4*)h + (long)idx0[rg] * 32 + q * 8;
      const float4* p1 = (const float4*)h + (long)idx1[rg] * 32 + q * 8;
      const float4* p2 = (const float4*)h + (long)idx2[rg] * 32 + q * 8;
      const float4* p3 = (const float4*)h + (long)idx3[rg] * 32 + q * 8;
#pragma unroll
      for (int c = 0; c < 8; ++c) {
        float4 v0 = p0[c], v1 = p1[c], v2 = p2[c], v3 = p3[c];
        int k0 = q * 32 + c * 4;
        lds_st4(sA, row, k0, v0.x + v2.x + v3.x, v0.y + v2.y + v3.y,
                v0.z + v2.z + v3.z, v0.w + v2.w + v3.w);
        lds_st4(tA, row, k0, v1.x, v1.y, v1.z, v1.w);
      }
    } else {
#pragma unroll
      for (int c = 0; c < 8; ++c) {
        int k0 = q * 32 + c * 4;
        lds_st4(sA, row, k0, 0.f, 0.f, 0.f, 0.f);
        lds_st4(tA, row, k0, 0.f, 0.f, 0.f, 0.f);
      }
    }
  }
  __syncthreads();
  mlp_layer<true>(sA, P, tA, P + 16384, b1, xA, lane, wr, wc);
  __syncthreads();
  mlp_layer<false>(xA, P + 32768, nullptr, nullptr, b2, sA, lane, wr, wc);
  __syncthreads();
  mlp_layer<false>(sA, P + 49152, nullptr, nullptr, b3, tA, lane, wr, wc);
  __syncthreads();
  {
    f32x4 acc = {0.f, 0.f, 0.f, 0.f};
#pragma unroll
    for (int ks = 0; ks < 4; ++ks) {
      int k0 = ks * 32 + (lane >> 4) * 8;
      f16x8 a = lds_frag(tA, wid * 16 + (lane & 15), k0);
      f16x8 b = *(const f16x8*)(P + 65536 + (lane & 15) * 128 + k0);
      acc = __builtin_amdgcn_mfma_f32_16x16x32_f16(a, b, acc, 0, 0, 0);
    }
    int col = lane & 15;
    if (col < 6) {
      float bov = bo[col];
#pragma unroll
      for (int r = 0; r < 4; ++r) {
        int rg = blk * 64 + wid * 16 + (lane >> 4) * 4 + r;
        if (rg < N_IMP) out[rg * 6 + col] = acc[r] + bov;
      }
    }
  }
}

extern "C" void kernel_launch(void* const* d_in, const int* in_sizes, int n_in,
                              void* d_out, int out_size, void* d_ws, size_t ws_size,
                              hipStream_t stream) {
  const float* h   = (const float*)d_in[0];
  const int* idx0  = (const int*)d_in[1];
  const int* idx1  = (const int*)d_in[2];
  const int* idx2  = (const int*)d_in[3];
  const int* idx3  = (const int*)d_in[4];
  const float* W1  = (const float*)d_in[5];
  const float* b1  = (const float*)d_in[6];
  const float* W2  = (const float*)d_in[7];
  const float* b2  = (const float*)d_in[8];
  const float* W3  = (const float*)d_in[9];
  const float* b3  = (const float*)d_in[10];
  const float* Wo  = (const float*)d_in[11];
  const float* bo  = (const float*)d_in[12];
  float* out = (float*)d_out;
  unsigned short* P = (unsigned short*)d_ws;

  prep_kernel<<<dim3(265), dim3(256), 0, stream>>>(W1, W2, W3, Wo, b1, P);
  if (ws_size >= WS_NEED) {
    unsigned short* uv = P + UV_OFF;
    atom_gemm<<<dim3((N_ATOMS + 63) / 64), dim3(256), 0, stream>>>(h, P, uv);
    janossy4<<<dim3(PERS_BLOCKS), dim3(256), 0, stream>>>(
        uv, idx0, idx1, idx2, idx3, b2, b3, bo, P, out);
  } else {
    janossy_kernel<<<dim3((N_IMP + 63) / 64), dim3(256), 0, stream>>>(
        h, idx0, idx1, idx2, idx3, b1, b2, b3, bo, P, out);
  }
}

// Round 6
// 245.243 us; speedup vs baseline: 1.9768x; 1.9768x over previous
//
#include <hip/hip_runtime.h>

typedef _Float16 f16x8 __attribute__((ext_vector_type(8)));
typedef float f32x4 __attribute__((ext_vector_type(4)));

#define N_IMP 300000
#define N_ATOMS 100000

__device__ __forceinline__ unsigned short f2h(float f) {
  _Float16 h = (_Float16)f;  // v_cvt_f16_f32, RNE
  return __builtin_bit_cast(unsigned short, h);
}
__device__ __forceinline__ unsigned int pk2(float a, float b) {
  return (unsigned int)f2h(a) | ((unsigned int)f2h(b) << 16);
}

// Packed f16 weights in d_ws (ushort units):
//  [0,16384)      Wa  [n][k]  = W1[0:128] + W1[256:384] + W1[384:512]
//  [16384,32768)  Wb  [n][k]  = 3*W1[128:256]
//  [32768,49152)  W2p [n][k]
//  [49152,65536)  W3p [n][k]
//  [65536,67584)  Wop [16][128] (cols 6..15 zero)
//  [67584,67712)  b1 as f16 (128)
//  [67712, +25.6M) uv [atom][256] f16: u = h@Wa (0:128), v = h@Wb (128:256)
#define PB1 67584
#define UV_OFF 67712
#define WS_NEED (2ull * (UV_OFF + (unsigned long long)N_ATOMS * 256))

__global__ __launch_bounds__(256) void prep_kernel(
    const float* __restrict__ W1, const float* __restrict__ W2,
    const float* __restrict__ W3, const float* __restrict__ Wo,
    const float* __restrict__ b1, unsigned short* __restrict__ P) {
  int t = blockIdx.x * 256 + threadIdx.x;  // grid 265 blocks = 67840 threads
  if (t >= UV_OFF) return;
  float v;
  if (t < 16384) {
    int n = t >> 7, k = t & 127;
    v = W1[k * 128 + n] + W1[(k + 256) * 128 + n] + W1[(k + 384) * 128 + n];
  } else if (t < 32768) {
    int i = t - 16384; int n = i >> 7, k = i & 127;
    v = 3.0f * W1[(k + 128) * 128 + n];
  } else if (t < 49152) {
    int i = t - 32768; int n = i >> 7, k = i & 127;
    v = W2[k * 128 + n];
  } else if (t < 65536) {
    int i = t - 49152; int n = i >> 7, k = i & 127;
    v = W3[k * 128 + n];
  } else if (t < PB1) {
    int i = t - 65536; int n = i >> 7, k = i & 127;
    v = (n < 6) ? Wo[k * 6 + n] : 0.0f;
  } else {
    v = b1[t - PB1];
  }
  P[t] = f2h(v);
}

// Swizzled LDS tile, row stride 256 B (G4: row-major D=128 f16 is a 16-way
// conflict on ds_read_b128 without the XOR). Involution: applied on the
// GLOBAL source offset at gather time and on the read offset (rule #21).
__device__ __forceinline__ int swz_off(int row, int kbyte) {
  return (row * 256 + kbyte) ^ ((row & 7) << 4);
}
__device__ __forceinline__ f16x8 lds_frag(const unsigned short* buf, int row, int k0) {
  return *(const f16x8*)((const char*)buf + swz_off(row, k0 * 2));
}
__device__ __forceinline__ void lds_st1(unsigned short* buf, int row, int col, unsigned short v) {
  *(unsigned short*)((char*)buf + swz_off(row, col * 2)) = v;
}
// Wave-local LDS fence: all lanes share one PC; lgkmcnt(0) drains this wave's
// LDS ops, "memory" clobber stops hipcc moving ds ops across it.
__device__ __forceinline__ void wave_lds_fence() {
  asm volatile("s_waitcnt lgkmcnt(0)" ::: "memory");
}
// Direct global->LDS (no VGPR round-trip). LDS dest = wave-uniform base +
// lane*16; global src is per-lane.
__device__ __forceinline__ void gload16(const void* g, void* l) {
  __builtin_amdgcn_global_load_lds(
      (const __attribute__((address_space(1))) unsigned int*)g,
      (__attribute__((address_space(3))) unsigned int*)l, 16, 0, 0);
}

// ============ atom precompute: uv = [h@Wa | h@Wb] (f16), LDS-free ============
__global__ __launch_bounds__(256, 4) void atom_gemm(
    const float* __restrict__ h, const unsigned short* __restrict__ P,
    unsigned short* __restrict__ uv) {
  const int lane = threadIdx.x & 63;
  const int wid = threadIdx.x >> 6;
  const int atom0 = blockIdx.x * 64 + wid * 16;
  if (atom0 >= N_ATOMS) return;  // per-wave guard; all atoms covered exactly
  const int col = lane & 15, hi = lane >> 4;

  const float4* ph = (const float4*)(h + (long)(atom0 + col) * 128);
  f16x8 bfr[4];
#pragma unroll
  for (int ks = 0; ks < 4; ++ks) {
    int k0 = ks * 32 + hi * 8;  // float index
    float4 v0 = ph[k0 / 4], v1 = ph[k0 / 4 + 1];
    f16x8 b;
    b[0] = (_Float16)v0.x; b[1] = (_Float16)v0.y; b[2] = (_Float16)v0.z; b[3] = (_Float16)v0.w;
    b[4] = (_Float16)v1.x; b[5] = (_Float16)v1.y; b[6] = (_Float16)v1.z; b[7] = (_Float16)v1.w;
    bfr[ks] = b;
  }
  f32x4 acc[16] = {};
#pragma unroll
  for (int ks = 0; ks < 4; ++ks) {
    int k0 = ks * 32 + hi * 8;
#pragma unroll
    for (int n = 0; n < 16; ++n) {
      f16x8 a = *(const f16x8*)(P + (n * 16 + col) * 128 + k0);
      acc[n] = __builtin_amdgcn_mfma_f32_16x16x32_f16(a, bfr[ks], acc[n], 0, 0, 0);
    }
  }
  unsigned short* dst = uv + (long)(atom0 + col) * 256 + hi * 4;
#pragma unroll
  for (int n = 0; n < 16; ++n) {
    uint2 w; w.x = pk2(acc[n][0], acc[n][1]); w.y = pk2(acc[n][2], acc[n][3]);
    *(uint2*)(dst + n * 16) = w;
  }
}

__device__ __forceinline__ void wave_epilogue(
    f32x4 (&acc)[8], const float* __restrict__ bias, unsigned short* Yb, int lane) {
#pragma unroll
  for (int n = 0; n < 8; ++n) {
    int col = n * 16 + (lane & 15);
    float bn = bias[col];
#pragma unroll
    for (int r = 0; r < 4; ++r) {
      float v = fmaxf(acc[n][r] + bn, 0.0f);
      lds_st1(Yb, (lane >> 4) * 4 + r, col, f2h(v));
    }
  }
}

// Main kernel: per 16-row wave-tile,
//  1) 16x global_load_lds_dwordx4 gathers (zero VGPR cost, all in flight),
//     source offsets pre-XOR-swizzled so linear LDS dest = swizzled tile;
//  2) vmcnt(0); ds_read_b128 the 4 sources, packed-f16 sum + b1 + relu -> x regs;
//  3) layer2 (x regs) -> Y (reuses gather buf) -> layer3 -> head -> coalesced out.
// No __syncthreads; everything wave-private.
__global__ __launch_bounds__(256) void janossy5(
    const unsigned short* __restrict__ uv, const int* __restrict__ idx0,
    const int* __restrict__ idx1, const int* __restrict__ idx2,
    const int* __restrict__ idx3, const float* __restrict__ b2,
    const float* __restrict__ b3, const float* __restrict__ bo,
    const unsigned short* __restrict__ P, float* __restrict__ out) {
  __shared__ __attribute__((aligned(16))) unsigned short L[4][8192];  // 16 KB/wave
  const int lane = threadIdx.x & 63;
  const int wid = threadIdx.x >> 6;
  const int tile = blockIdx.x * 4 + wid;
  if (tile * 16 >= N_IMP) return;  // wave-uniform guard
  const int r0 = tile * 16;
  const int row = lane & 15, hi = lane >> 4;
  const int c16 = row * 16;  // NOTE: used only below as (lane&15)*16 for gathers
  unsigned short* G = L[wid];
  const char* uvB = (const char*)uv;

  // ---- load this lane's 16 index values (static-indexed array -> VGPRs) ----
  int jj[4][4];  // [g][src]
#pragma unroll
  for (int g = 0; g < 4; ++g) {
    int rr = r0 + g * 4 + hi;
    jj[g][0] = idx0[rr]; jj[g][1] = idx1[rr];
    jj[g][2] = idx2[rr]; jj[g][3] = idx3[rr];
  }

  // ---- issue 16 gathers, source pre-swizzled, LDS dest linear ----
#pragma unroll
  for (int g = 0; g < 4; ++g) {
    const int grow = g * 4 + hi;                       // LDS row this lane fills
    const unsigned int colb = (unsigned int)(c16 ^ ((grow & 7) << 4));
    char* base = (char*)G + g * 1024;
    gload16(uvB + (long)jj[g][0] * 512 + colb,       base);            // u[idx0]
    gload16(uvB + (long)jj[g][2] * 512 + colb,       base + 4096);     // u[idx2]
    gload16(uvB + (long)jj[g][3] * 512 + colb,       base + 8192);     // u[idx3]
    gload16(uvB + (long)jj[g][1] * 512 + 256 + colb, base + 12288);    // v[idx1]
  }
  asm volatile("s_waitcnt vmcnt(0)" ::: "memory");
  __builtin_amdgcn_sched_barrier(0);

  // ---- consume: x = relu(u0+u2+u3+v1+b1), packed f16, A-frag layout ----
  f16x8 x[4];
#pragma unroll
  for (int ks = 0; ks < 4; ++ks) {
    int k0 = ks * 32 + hi * 8;
    f16x8 s = lds_frag(G, row, k0) + lds_frag(G + 2048, row, k0) +
              lds_frag(G + 4096, row, k0) + lds_frag(G + 6144, row, k0);
    s = s + *(const f16x8*)(P + PB1 + k0);
    f16x8 z = {};
    x[ks] = __builtin_elementwise_max(s, z);
  }

  // ---- layer 2 (A = x from registers) ----
  f32x4 acc[8] = {};
#pragma unroll
  for (int ks = 0; ks < 4; ++ks) {
    int k0 = ks * 32 + hi * 8;
#pragma unroll
    for (int n = 0; n < 8; ++n) {
      f16x8 b = *(const f16x8*)(P + 32768 + (n * 16 + row) * 128 + k0);
      acc[n] = __builtin_amdgcn_mfma_f32_16x16x32_f16(x[ks], b, acc[n], 0, 0, 0);
    }
  }
  wave_lds_fence();                 // gather-buf reads fully drained
  wave_epilogue(acc, b2, G, lane);  // Y reuses G[0,2048)
  wave_lds_fence();

  // ---- layer 3 ----
  f32x4 acc3[8] = {};
#pragma unroll
  for (int ks = 0; ks < 4; ++ks) {
    int k0 = ks * 32 + hi * 8;
    f16x8 a = lds_frag(G, row, k0);
#pragma unroll
    for (int n = 0; n < 8; ++n) {
      f16x8 b = *(const f16x8*)(P + 49152 + (n * 16 + row) * 128 + k0);
      acc3[n] = __builtin_amdgcn_mfma_f32_16x16x32_f16(a, b, acc3[n], 0, 0, 0);
    }
  }
  wave_lds_fence();
  wave_epilogue(acc3, b3, G, lane);
  wave_lds_fence();

  // ---- head + coalesced store (LDS bounce -> contiguous 384 B) ----
  {
    f32x4 acch = {0.f, 0.f, 0.f, 0.f};
#pragma unroll
    for (int ks = 0; ks < 4; ++ks) {
      int k0 = ks * 32 + hi * 8;
      f16x8 a = lds_frag(G, row, k0);
      f16x8 b = *(const f16x8*)(P + 65536 + row * 128 + k0);
      acch = __builtin_amdgcn_mfma_f32_16x16x32_f16(a, b, acch, 0, 0, 0);
    }
    float* OS = (float*)(G + 2048);  // 384 B staging in consumed src-1 region
    if (row < 6) {
      float bov = bo[row];
#pragma unroll
      for (int r = 0; r < 4; ++r) OS[(hi * 4 + r) * 6 + row] = acch[r] + bov;
    }
    wave_lds_fence();
    if (lane < 48) {
      float2 v = ((const float2*)OS)[lane];
      *(float2*)(out + (long)tile * 96 + lane * 2) = v;
    }
  }
}

// ===================== fallback path (R1, needs only 136 KB ws) =====================

__device__ __forceinline__ void lds_st4(unsigned short* buf, int row, int k0,
                                        float a, float b, float c, float d) {
  uint2 u; u.x = pk2(a, b); u.y = pk2(c, d);
  *(uint2*)((char*)buf + swz_off(row, k0 * 2)) = u;
}

template <bool DUAL>
__device__ __forceinline__ void mlp_layer(
    const unsigned short* A1, const unsigned short* __restrict__ B1,
    const unsigned short* A2, const unsigned short* __restrict__ B2,
    const float* __restrict__ bias, unsigned short* Obuf, int lane, int wr, int wc) {
  f32x4 acc[2][4] = {};
#pragma unroll
  for (int ks = 0; ks < 4; ++ks) {
    int k0 = ks * 32 + (lane >> 4) * 8;
    f16x8 a0 = lds_frag(A1, wr * 32 + (lane & 15), k0);
    f16x8 a1 = lds_frag(A1, wr * 32 + 16 + (lane & 15), k0);
#pragma unroll
    for (int n = 0; n < 4; ++n) {
      int col = wc * 64 + n * 16 + (lane & 15);
      f16x8 b = *(const f16x8*)(B1 + col * 128 + k0);
      acc[0][n] = __builtin_amdgcn_mfma_f32_16x16x32_f16(a0, b, acc[0][n], 0, 0, 0);
      acc[1][n] = __builtin_amdgcn_mfma_f32_16x16x32_f16(a1, b, acc[1][n], 0, 0, 0);
    }
  }
  if constexpr (DUAL) {
#pragma unroll
    for (int ks = 0; ks < 4; ++ks) {
      int k0 = ks * 32 + (lane >> 4) * 8;
      f16x8 a0 = lds_frag(A2, wr * 32 + (lane & 15), k0);
      f16x8 a1 = lds_frag(A2, wr * 32 + 16 + (lane & 15), k0);
#pragma unroll
      for (int n = 0; n < 4; ++n) {
        int col = wc * 64 + n * 16 + (lane & 15);
        f16x8 b = *(const f16x8*)(B2 + col * 128 + k0);
        acc[0][n] = __builtin_amdgcn_mfma_f32_16x16x32_f16(a0, b, acc[0][n], 0, 0, 0);
        acc[1][n] = __builtin_amdgcn_mfma_f32_16x16x32_f16(a1, b, acc[1][n], 0, 0, 0);
      }
    }
  }
#pragma unroll
  for (int n = 0; n < 4; ++n) {
    int col = wc * 64 + n * 16 + (lane & 15);
    float bn = bias[col];
#pragma unroll
    for (int m = 0; m < 2; ++m) {
#pragma unroll
      for (int r = 0; r < 4; ++r) {
        float v = fmaxf(acc[m][n][r] + bn, 0.0f);
        lds_st1(Obuf, wr * 32 + m * 16 + (lane >> 4) * 4 + r, col, f2h(v));
      }
    }
  }
}

__global__ __launch_bounds__(256) void janossy_kernel(
    const float* __restrict__ h, const int* __restrict__ idx0,
    const int* __restrict__ idx1, const int* __restrict__ idx2,
    const int* __restrict__ idx3, const float* __restrict__ b1,
    const float* __restrict__ b2, const float* __restrict__ b3,
    const float* __restrict__ bo, const unsigned short* __restrict__ P,
    float* __restrict__ out) {
  __shared__ __attribute__((aligned(16))) unsigned short sA[64 * 128];
  __shared__ __attribute__((aligned(16))) unsigned short tA[64 * 128];
  __shared__ __attribute__((aligned(16))) unsigned short xA[64 * 128];
  const int tid = threadIdx.x;
  const int lane = tid & 63;
  const int wid = tid >> 6;
  const int wr = wid & 1, wc = wid >> 1;
  const int blk = blockIdx.x;
  {
    int row = tid >> 2, q = tid & 3;
    int rg = blk * 64 + row;
    if (rg < N_IMP) {
      const float4* p0 = (const float4*)h + (long)idx0[rg] * 32 + q * 8;
      const float4* p1 = (const float4*)h + (long)idx1[rg] * 32 + q * 8;
      const float4* p2 = (const float4*)h + (long)idx2[rg] * 32 + q * 8;
      const float4* p3 = (const float4*)h + (long)idx3[rg] * 32 + q * 8;
#pragma unroll
      for (int c = 0; c < 8; ++c) {
        float4 v0 = p0[c], v1 = p1[c], v2 = p2[c], v3 = p3[c];
        int k0 = q * 32 + c * 4;
        lds_st4(sA, row, k0, v0.x + v2.x + v3.x, v0.y + v2.y + v3.y,
                v0.z + v2.z + v3.z, v0.w + v2.w + v3.w);
        lds_st4(tA, row, k0, v1.x, v1.y, v1.z, v1.w);
      }
    } else {
#pragma unroll
      for (int c = 0; c < 8; ++c) {
        int k0 = q * 32 + c * 4;
        lds_st4(sA, row, k0, 0.f, 0.f, 0.f, 0.f);
        lds_st4(tA, row, k0, 0.f, 0.f, 0.f, 0.f);
      }
    }
  }
  __syncthreads();
  mlp_layer<true>(sA, P, tA, P + 16384, b1, xA, lane, wr, wc);
  __syncthreads();
  mlp_layer<false>(xA, P + 32768, nullptr, nullptr, b2, sA, lane, wr, wc);
  __syncthreads();
  mlp_layer<false>(sA, P + 49152, nullptr, nullptr, b3, tA, lane, wr, wc);
  __syncthreads();
  {
    f32x4 acc = {0.f, 0.f, 0.f, 0.f};
#pragma unroll
    for (int ks = 0; ks < 4; ++ks) {
      int k0 = ks * 32 + (lane >> 4) * 8;
      f16x8 a = lds_frag(tA, wid * 16 + (lane & 15), k0);
      f16x8 b = *(const f16x8*)(P + 65536 + (lane & 15) * 128 + k0);
      acc = __builtin_amdgcn_mfma_f32_16x16x32_f16(a, b, acc, 0, 0, 0);
    }
    int col = lane & 15;
    if (col < 6) {
      float bov = bo[col];
#pragma unroll
      for (int r = 0; r < 4; ++r) {
        int rg = blk * 64 + wid * 16 + (lane >> 4) * 4 + r;
        if (rg < N_IMP) out[rg * 6 + col] = acc[r] + bov;
      }
    }
  }
}

extern "C" void kernel_launch(void* const* d_in, const int* in_sizes, int n_in,
                              void* d_out, int out_size, void* d_ws, size_t ws_size,
                              hipStream_t stream) {
  const float* h   = (const float*)d_in[0];
  const int* idx0  = (const int*)d_in[1];
  const int* idx1  = (const int*)d_in[2];
  const int* idx2  = (const int*)d_in[3];
  const int* idx3  = (const int*)d_in[4];
  const float* W1  = (const float*)d_in[5];
  const float* b1  = (const float*)d_in[6];
  const float* W2  = (const float*)d_in[7];
  const float* b2  = (const float*)d_in[8];
  const float* W3  = (const float*)d_in[9];
  const float* b3  = (const float*)d_in[10];
  const float* Wo  = (const float*)d_in[11];
  const float* bo  = (const float*)d_in[12];
  float* out = (float*)d_out;
  unsigned short* P = (unsigned short*)d_ws;

  prep_kernel<<<dim3(265), dim3(256), 0, stream>>>(W1, W2, W3, Wo, b1, P);
  if (ws_size >= WS_NEED) {
    unsigned short* uv = P + UV_OFF;
    atom_gemm<<<dim3((N_ATOMS + 63) / 64), dim3(256), 0, stream>>>(h, P, uv);
    janossy5<<<dim3((N_IMP / 16 + 3) / 4), dim3(256), 0, stream>>>(
        uv, idx0, idx1, idx2, idx3, b2, b3, bo, P, out);
  } else {
    janossy_kernel<<<dim3((N_IMP + 63) / 64), dim3(256), 0, stream>>>(
        h, idx0, idx1, idx2, idx3, b1, b2, b3, bo, P, out);
  }
}

// Round 7
// 191.230 us; speedup vs baseline: 2.5352x; 1.2824x over previous
//
#include <hip/hip_runtime.h>

typedef _Float16 f16x8 __attribute__((ext_vector_type(8)));
typedef float f32x4 __attribute__((ext_vector_type(4)));

#define N_IMP 300000
#define N_ATOMS 100000
#define NTILE (N_IMP / 32)   // 9375 tiles of 32 rows
#define GRID_J6 1024

__device__ __forceinline__ unsigned short f2h(float f) {
  _Float16 h = (_Float16)f;  // v_cvt_f16_f32, RNE
  return __builtin_bit_cast(unsigned short, h);
}
__device__ __forceinline__ unsigned int pk2(float a, float b) {
  return (unsigned int)f2h(a) | ((unsigned int)f2h(b) << 16);
}

// Packed f16 weights in d_ws (ushort units):
//  [0,16384)      Wa  [n][k]  = W1[0:128] + W1[256:384] + W1[384:512]
//  [16384,32768)  Wb  [n][k]  = 3*W1[128:256]
//  [32768,49152)  W2p [n][k]
//  [49152,65536)  W3p [n][k]
//  [65536,67584)  Wop [16][128] (cols 6..15 zero)
//  [67584,67712)  b1 as f16 (128)
//  [67712, +25.6M) uv [atom][256] f16: u = h@Wa (0:128), v = h@Wb (128:256)
#define PB1 67584
#define UV_OFF 67712
#define WS_NEED (2ull * (UV_OFF + (unsigned long long)N_ATOMS * 256))

__global__ __launch_bounds__(256) void prep_kernel(
    const float* __restrict__ W1, const float* __restrict__ W2,
    const float* __restrict__ W3, const float* __restrict__ Wo,
    const float* __restrict__ b1, unsigned short* __restrict__ P) {
  int t = blockIdx.x * 256 + threadIdx.x;  // grid 265 blocks = 67840 threads
  if (t >= UV_OFF) return;
  float v;
  if (t < 16384) {
    int n = t >> 7, k = t & 127;
    v = W1[k * 128 + n] + W1[(k + 256) * 128 + n] + W1[(k + 384) * 128 + n];
  } else if (t < 32768) {
    int i = t - 16384; int n = i >> 7, k = i & 127;
    v = 3.0f * W1[(k + 128) * 128 + n];
  } else if (t < 49152) {
    int i = t - 32768; int n = i >> 7, k = i & 127;
    v = W2[k * 128 + n];
  } else if (t < 65536) {
    int i = t - 49152; int n = i >> 7, k = i & 127;
    v = W3[k * 128 + n];
  } else if (t < PB1) {
    int i = t - 65536; int n = i >> 7, k = i & 127;
    v = (n < 6) ? Wo[k * 6 + n] : 0.0f;
  } else {
    v = b1[t - PB1];
  }
  P[t] = f2h(v);
}

// Swizzled LDS row, stride 256 B (G4: row-major D=128 f16 is a 16-way conflict
// on ds_read_b128 without the XOR). Involution applied on the GLOBAL source
// offset at gather time and on the read offset (rule #21).
__device__ __forceinline__ int swz_off(int row, int kbyte) {
  return (row * 256 + kbyte) ^ ((row & 7) << 4);
}
__device__ __forceinline__ f16x8 lds_frag(const unsigned short* buf, int row, int k0) {
  return *(const f16x8*)((const char*)buf + swz_off(row, k0 * 2));
}
__device__ __forceinline__ void lds_st1(unsigned short* buf, int row, int col, unsigned short v) {
  *(unsigned short*)((char*)buf + swz_off(row, col * 2)) = v;
}
// Wave-local LDS fence: all lanes share one PC; lgkmcnt(0) drains this wave's
// LDS ops, "memory" clobber stops hipcc moving ds ops across it.
__device__ __forceinline__ void wave_lds_fence() {
  asm volatile("s_waitcnt lgkmcnt(0)" ::: "memory");
}
// Direct global->LDS (no VGPR round-trip). LDS dest = wave-uniform base +
// lane*16; global src is per-lane.
__device__ __forceinline__ void gload16(const void* g, void* l) {
  __builtin_amdgcn_global_load_lds(
      (const __attribute__((address_space(1))) unsigned int*)g,
      (__attribute__((address_space(3))) unsigned int*)l, 16, 0, 0);
}

// ============ atom precompute: uv = [h@Wa | h@Wb] (f16), LDS-free ============
__global__ __launch_bounds__(256, 4) void atom_gemm(
    const float* __restrict__ h, const unsigned short* __restrict__ P,
    unsigned short* __restrict__ uv) {
  const int lane = threadIdx.x & 63;
  const int wid = threadIdx.x >> 6;
  const int atom0 = blockIdx.x * 64 + wid * 16;
  if (atom0 >= N_ATOMS) return;
  const int col = lane & 15, hi = lane >> 4;

  const float4* ph = (const float4*)(h + (long)(atom0 + col) * 128);
  f16x8 bfr[4];
#pragma unroll
  for (int ks = 0; ks < 4; ++ks) {
    int k0 = ks * 32 + hi * 8;  // float index
    float4 v0 = ph[k0 / 4], v1 = ph[k0 / 4 + 1];
    f16x8 b;
    b[0] = (_Float16)v0.x; b[1] = (_Float16)v0.y; b[2] = (_Float16)v0.z; b[3] = (_Float16)v0.w;
    b[4] = (_Float16)v1.x; b[5] = (_Float16)v1.y; b[6] = (_Float16)v1.z; b[7] = (_Float16)v1.w;
    bfr[ks] = b;
  }
  f32x4 acc[16] = {};
#pragma unroll
  for (int ks = 0; ks < 4; ++ks) {
    int k0 = ks * 32 + hi * 8;
#pragma unroll
    for (int n = 0; n < 16; ++n) {
      f16x8 a = *(const f16x8*)(P + (n * 16 + col) * 128 + k0);
      acc[n] = __builtin_amdgcn_mfma_f32_16x16x32_f16(a, bfr[ks], acc[n], 0, 0, 0);
    }
  }
  unsigned short* dst = uv + (long)(atom0 + col) * 256 + hi * 4;
#pragma unroll
  for (int n = 0; n < 16; ++n) {
    uint2 w; w.x = pk2(acc[n][0], acc[n][1]); w.y = pk2(acc[n][2], acc[n][3]);
    *(uint2*)(dst + n * 16) = w;
  }
}

// ===================== janossy6: persistent 1-wave pipeline =====================
// Per 32-row tile: vmcnt(0) [gathers landed] -> consume into x regs ->
// lgkmcnt(0) -> reissue SAME buffer with next tile's 32 gathers -> compute
// layers 2/3/head of current tile while they fly. Block = 1 wave; LDS = 40 KB
// (32 KB gather buf + 8 KB Y) -> exactly 4 blocks/CU.
__global__ __launch_bounds__(64, 1) void janossy6(
    const unsigned short* __restrict__ uv, const int* __restrict__ idx0,
    const int* __restrict__ idx1, const int* __restrict__ idx2,
    const int* __restrict__ idx3, const float* __restrict__ b2,
    const float* __restrict__ b3, const float* __restrict__ bo,
    const unsigned short* __restrict__ P, float* __restrict__ out) {
  __shared__ __attribute__((aligned(16))) unsigned short G[16384];  // 32 KB
  __shared__ __attribute__((aligned(16))) unsigned short Yb[4096];  // 8 KB
  const int lane = threadIdx.x & 63;
  const int row = lane & 15, hi = lane >> 4;
  const char* uvB = (const char*)uv;
  const unsigned int c16 = (unsigned int)(row * 16);

  // loop-invariant preloads
  f16x8 b1f[4];
#pragma unroll
  for (int ks = 0; ks < 4; ++ks) b1f[ks] = *(const f16x8*)(P + PB1 + ks * 32 + hi * 8);
  const float bov = (row < 6) ? bo[row] : 0.0f;

  int jj[8][4];  // next-tile indices, rows 4g+hi (statically indexed only)

  auto ld_idx = [&](int tt) {
#pragma unroll
    for (int g = 0; g < 8; ++g) {
      int rr = tt * 32 + g * 4 + hi;
      jj[g][0] = idx0[rr]; jj[g][1] = idx1[rr];
      jj[g][2] = idx2[rr]; jj[g][3] = idx3[rr];
    }
  };
  // 32 gathers: call (g,s) fills rows 4g..4g+3 of source s (1024 B linear
  // dest), source offset pre-XOR-swizzled (key = row&7).
  auto issue_g = [&]() {
#pragma unroll
    for (int g = 0; g < 8; ++g) {
      const unsigned int colb = c16 ^ (unsigned int)((((g * 4) + hi) & 7) << 4);
      char* base = (char*)G + g * 1024;
      gload16(uvB + (long)jj[g][0] * 512 + colb,       base);           // u[idx0]
      gload16(uvB + (long)jj[g][2] * 512 + colb,       base + 8192);    // u[idx2]
      gload16(uvB + (long)jj[g][3] * 512 + colb,       base + 16384);   // u[idx3]
      gload16(uvB + (long)jj[g][1] * 512 + 256 + colb, base + 24576);   // v[idx1]
    }
  };

  int t = blockIdx.x;
  if (t >= NTILE) return;
  // ---- prologue ----
  ld_idx(t);
  asm volatile("s_waitcnt vmcnt(0)" ::: "memory");
  issue_g();                       // gathers for first tile
  int tn = t + GRID_J6;
  if (tn < NTILE) ld_idx(tn);      // prefetch next indices

  for (;;) {
    const bool hn = (tn < NTILE);  // wave-uniform
    asm volatile("s_waitcnt vmcnt(0)" ::: "memory");  // gathers(t) + idx landed
    __builtin_amdgcn_sched_barrier(0);

    // ---- consume: x[m][ks] = relu(u0+u2+u3+v1+b1), packed f16 ----
    f16x8 x0[4], x1[4];
#pragma unroll
    for (int ks = 0; ks < 4; ++ks) {
      int k0 = ks * 32 + hi * 8;
      f16x8 z = {};
      f16x8 s0 = lds_frag(G, row, k0) + lds_frag(G + 4096, row, k0) +
                 lds_frag(G + 8192, row, k0) + lds_frag(G + 12288, row, k0) + b1f[ks];
      x0[ks] = __builtin_elementwise_max(s0, z);
      f16x8 s1 = lds_frag(G, 16 + row, k0) + lds_frag(G + 4096, 16 + row, k0) +
                 lds_frag(G + 8192, 16 + row, k0) + lds_frag(G + 12288, 16 + row, k0) + b1f[ks];
      x1[ks] = __builtin_elementwise_max(s1, z);
    }
    wave_lds_fence();  // all ds_reads of G retired -> buffer reusable

    // ---- reissue buffer with next tile's gathers; prefetch idx 2 ahead ----
    if (hn) {
      issue_g();
      int t2 = tn + GRID_J6;
      if (t2 < NTILE) ld_idx(t2);
    }

    // ---- layer 2 (A = x regs; B reused across both m halves) ----
    f32x4 acc[2][8] = {};
#pragma unroll
    for (int ks = 0; ks < 4; ++ks) {
      int k0 = ks * 32 + hi * 8;
#pragma unroll
      for (int n = 0; n < 8; ++n) {
        f16x8 b = *(const f16x8*)(P + 32768 + (n * 16 + row) * 128 + k0);
        acc[0][n] = __builtin_amdgcn_mfma_f32_16x16x32_f16(x0[ks], b, acc[0][n], 0, 0, 0);
        acc[1][n] = __builtin_amdgcn_mfma_f32_16x16x32_f16(x1[ks], b, acc[1][n], 0, 0, 0);
      }
    }
#pragma unroll
    for (int m = 0; m < 2; ++m)
#pragma unroll
      for (int n = 0; n < 8; ++n) {
        int col = n * 16 + row;
        float bn = b2[col];
#pragma unroll
        for (int r = 0; r < 4; ++r) {
          float v = fmaxf(acc[m][n][r] + bn, 0.0f);
          lds_st1(Yb, m * 16 + hi * 4 + r, col, f2h(v));
        }
      }
    wave_lds_fence();

    // ---- layer 3 ----
    f32x4 acc3[2][8] = {};
#pragma unroll
    for (int ks = 0; ks < 4; ++ks) {
      int k0 = ks * 32 + hi * 8;
      f16x8 a0 = lds_frag(Yb, row, k0);
      f16x8 a1 = lds_frag(Yb, 16 + row, k0);
#pragma unroll
      for (int n = 0; n < 8; ++n) {
        f16x8 b = *(const f16x8*)(P + 49152 + (n * 16 + row) * 128 + k0);
        acc3[0][n] = __builtin_amdgcn_mfma_f32_16x16x32_f16(a0, b, acc3[0][n], 0, 0, 0);
        acc3[1][n] = __builtin_amdgcn_mfma_f32_16x16x32_f16(a1, b, acc3[1][n], 0, 0, 0);
      }
    }
    wave_lds_fence();  // Yb reads done before overwrite
#pragma unroll
    for (int m = 0; m < 2; ++m)
#pragma unroll
      for (int n = 0; n < 8; ++n) {
        int col = n * 16 + row;
        float bn = b3[col];
#pragma unroll
        for (int r = 0; r < 4; ++r) {
          float v = fmaxf(acc3[m][n][r] + bn, 0.0f);
          lds_st1(Yb, m * 16 + hi * 4 + r, col, f2h(v));
        }
      }
    wave_lds_fence();

    // ---- head + coalesced store ----
    {
      f32x4 acch[2] = {};
#pragma unroll
      for (int ks = 0; ks < 4; ++ks) {
        int k0 = ks * 32 + hi * 8;
        f16x8 a0 = lds_frag(Yb, row, k0);
        f16x8 a1 = lds_frag(Yb, 16 + row, k0);
        f16x8 b = *(const f16x8*)(P + 65536 + row * 128 + k0);
        acch[0] = __builtin_amdgcn_mfma_f32_16x16x32_f16(a0, b, acch[0], 0, 0, 0);
        acch[1] = __builtin_amdgcn_mfma_f32_16x16x32_f16(a1, b, acch[1], 0, 0, 0);
      }
      wave_lds_fence();  // Yb A-frag reads done before OS overwrite
      float* OS = (float*)Yb;  // 768 B staging
      if (row < 6) {
#pragma unroll
        for (int m = 0; m < 2; ++m)
#pragma unroll
          for (int r = 0; r < 4; ++r)
            OS[(m * 16 + hi * 4 + r) * 6 + row] = acch[m][r] + bov;
      }
      wave_lds_fence();
      float* ob = out + (long)t * 192;
      {
        float2 v0 = ((const float2*)OS)[lane];
        *(float2*)(ob + lane * 2) = v0;
      }
      if (lane < 32) {
        float2 v1 = ((const float2*)OS)[64 + lane];
        *(float2*)(ob + 128 + lane * 2) = v1;
      }
      wave_lds_fence();
    }

    if (!hn) break;
    t = tn;
    tn = t + GRID_J6;
  }
}

// ===================== fallback path (R1, needs only 136 KB ws) =====================

__device__ __forceinline__ void lds_st4(unsigned short* buf, int row, int k0,
                                        float a, float b, float c, float d) {
  uint2 u; u.x = pk2(a, b); u.y = pk2(c, d);
  *(uint2*)((char*)buf + swz_off(row, k0 * 2)) = u;
}

template <bool DUAL>
__device__ __forceinline__ void mlp_layer(
    const unsigned short* A1, const unsigned short* __restrict__ B1,
    const unsigned short* A2, const unsigned short* __restrict__ B2,
    const float* __restrict__ bias, unsigned short* Obuf, int lane, int wr, int wc) {
  f32x4 acc[2][4] = {};
#pragma unroll
  for (int ks = 0; ks < 4; ++ks) {
    int k0 = ks * 32 + (lane >> 4) * 8;
    f16x8 a0 = lds_frag(A1, wr * 32 + (lane & 15), k0);
    f16x8 a1 = lds_frag(A1, wr * 32 + 16 + (lane & 15), k0);
#pragma unroll
    for (int n = 0; n < 4; ++n) {
      int col = wc * 64 + n * 16 + (lane & 15);
      f16x8 b = *(const f16x8*)(B1 + col * 128 + k0);
      acc[0][n] = __builtin_amdgcn_mfma_f32_16x16x32_f16(a0, b, acc[0][n], 0, 0, 0);
      acc[1][n] = __builtin_amdgcn_mfma_f32_16x16x32_f16(a1, b, acc[1][n], 0, 0, 0);
    }
  }
  if constexpr (DUAL) {
#pragma unroll
    for (int ks = 0; ks < 4; ++ks) {
      int k0 = ks * 32 + (lane >> 4) * 8;
      f16x8 a0 = lds_frag(A2, wr * 32 + (lane & 15), k0);
      f16x8 a1 = lds_frag(A2, wr * 32 + 16 + (lane & 15), k0);
#pragma unroll
      for (int n = 0; n < 4; ++n) {
        int col = wc * 64 + n * 16 + (lane & 15);
        f16x8 b = *(const f16x8*)(B2 + col * 128 + k0);
        acc[0][n] = __builtin_amdgcn_mfma_f32_16x16x32_f16(a0, b, acc[0][n], 0, 0, 0);
        acc[1][n] = __builtin_amdgcn_mfma_f32_16x16x32_f16(a1, b, acc[1][n], 0, 0, 0);
      }
    }
  }
#pragma unroll
  for (int n = 0; n < 4; ++n) {
    int col = wc * 64 + n * 16 + (lane & 15);
    float bn = bias[col];
#pragma unroll
    for (int m = 0; m < 2; ++m) {
#pragma unroll
      for (int r = 0; r < 4; ++r) {
        float v = fmaxf(acc[m][n][r] + bn, 0.0f);
        lds_st1(Obuf, wr * 32 + m * 16 + (lane >> 4) * 4 + r, col, f2h(v));
      }
    }
  }
}

__global__ __launch_bounds__(256) void janossy_kernel(
    const float* __restrict__ h, const int* __restrict__ idx0,
    const int* __restrict__ idx1, const int* __restrict__ idx2,
    const int* __restrict__ idx3, const float* __restrict__ b1,
    const float* __restrict__ b2, const float* __restrict__ b3,
    const float* __restrict__ bo, const unsigned short* __restrict__ P,
    float* __restrict__ out) {
  __shared__ __attribute__((aligned(16))) unsigned short sA[64 * 128];
  __shared__ __attribute__((aligned(16))) unsigned short tA[64 * 128];
  __shared__ __attribute__((aligned(16))) unsigned short xA[64 * 128];
  const int tid = threadIdx.x;
  const int lane = tid & 63;
  const int wid = tid >> 6;
  const int wr = wid & 1, wc = wid >> 1;
  const int blk = blockIdx.x;
  {
    int row = tid >> 2, q = tid & 3;
    int rg = blk * 64 + row;
    if (rg < N_IMP) {
      const float4* p0 = (const float4*)h + (long)idx0[rg] * 32 + q * 8;
      const float4* p1 = (const float4*)h + (long)idx1[rg] * 32 + q * 8;
      const float4* p2 = (const float4*)h + (long)idx2[rg] * 32 + q * 8;
      const float4* p3 = (const float4*)h + (long)idx3[rg] * 32 + q * 8;
#pragma unroll
      for (int c = 0; c < 8; ++c) {
        float4 v0 = p0[c], v1 = p1[c], v2 = p2[c], v3 = p3[c];
        int k0 = q * 32 + c * 4;
        lds_st4(sA, row, k0, v0.x + v2.x + v3.x, v0.y + v2.y + v3.y,
                v0.z + v2.z + v3.z, v0.w + v2.w + v3.w);
        lds_st4(tA, row, k0, v1.x, v1.y, v1.z, v1.w);
      }
    } else {
#pragma unroll
      for (int c = 0; c < 8; ++c) {
        int k0 = q * 32 + c * 4;
        lds_st4(sA, row, k0, 0.f, 0.f, 0.f, 0.f);
        lds_st4(tA, row, k0, 0.f, 0.f, 0.f, 0.f);
      }
    }
  }
  __syncthreads();
  mlp_layer<true>(sA, P, tA, P + 16384, b1, xA, lane, wr, wc);
  __syncthreads();
  mlp_layer<false>(xA, P + 32768, nullptr, nullptr, b2, sA, lane, wr, wc);
  __syncthreads();
  mlp_layer<false>(sA, P + 49152, nullptr, nullptr, b3, tA, lane, wr, wc);
  __syncthreads();
  {
    f32x4 acc = {0.f, 0.f, 0.f, 0.f};
#pragma unroll
    for (int ks = 0; ks < 4; ++ks) {
      int k0 = ks * 32 + (lane >> 4) * 8;
      f16x8 a = lds_frag(tA, wid * 16 + (lane & 15), k0);
      f16x8 b = *(const f16x8*)(P + 65536 + (lane & 15) * 128 + k0);
      acc = __builtin_amdgcn_mfma_f32_16x16x32_f16(a, b, acc, 0, 0, 0);
    }
    int col = lane & 15;
    if (col < 6) {
      float bov = bo[col];
#pragma unroll
      for (int r = 0; r < 4; ++r) {
        int rg = blk * 64 + wid * 16 + (lane >> 4) * 4 + r;
        if (rg < N_IMP) out[rg * 6 + col] = acc[r] + bov;
      }
    }
  }
}

extern "C" void kernel_launch(void* const* d_in, const int* in_sizes, int n_in,
                              void* d_out, int out_size, void* d_ws, size_t ws_size,
                              hipStream_t stream) {
  const float* h   = (const float*)d_in[0];
  const int* idx0  = (const int*)d_in[1];
  const int* idx1  = (const int*)d_in[2];
  const int* idx2  = (const int*)d_in[3];
  const int* idx3  = (const int*)d_in[4];
  const float* W1  = (const float*)d_in[5];
  const float* b1  = (const float*)d_in[6];
  const float* W2  = (const float*)d_in[7];
  const float* b2  = (const float*)d_in[8];
  const float* W3  = (const float*)d_in[9];
  const float* b3  = (const float*)d_in[10];
  const float* Wo  = (const float*)d_in[11];
  const float* bo  = (const float*)d_in[12];
  float* out = (float*)d_out;
  unsigned short* P = (unsigned short*)d_ws;

  prep_kernel<<<dim3(265), dim3(256), 0, stream>>>(W1, W2, W3, Wo, b1, P);
  if (ws_size >= WS_NEED) {
    unsigned short* uv = P + UV_OFF;
    atom_gemm<<<dim3((N_ATOMS + 63) / 64), dim3(256), 0, stream>>>(h, P, uv);
    janossy6<<<dim3(GRID_J6), dim3(64), 0, stream>>>(
        uv, idx0, idx1, idx2, idx3, b2, b3, bo, P, out);
  } else {
    janossy_kernel<<<dim3((N_IMP + 63) / 64), dim3(256), 0, stream>>>(
        h, idx0, idx1, idx2, idx3, b1, b2, b3, bo, P, out);
  }
}

// Round 8
// 133.853 us; speedup vs baseline: 3.6219x; 1.4287x over previous
//
#include <hip/hip_runtime.h>

typedef _Float16 f16x8 __attribute__((ext_vector_type(8)));
typedef float f32x4 __attribute__((ext_vector_type(4)));

#define N_IMP 300000
#define N_ATOMS 100000
#define NT16 (N_IMP / 16)        // 18750 16-row tiles
#define J7_BLOCKS 256
#define J7_WAVES (J7_BLOCKS * 4) // 1024 persistent waves
#define AT_TILES (N_ATOMS / 16)  // 6250
#define AG_BLOCKS 512
#define AG_WAVES (AG_BLOCKS * 4) // 2048

__device__ __forceinline__ unsigned short f2h(float f) {
  _Float16 h = (_Float16)f;  // v_cvt_f16_f32, RNE
  return __builtin_bit_cast(unsigned short, h);
}
__device__ __forceinline__ unsigned int pk2(float a, float b) {
  return (unsigned int)f2h(a) | ((unsigned int)f2h(b) << 16);
}

// Packed f16 weights in d_ws (ushort units):
//  [0,16384)      Wa  [n][k]  = W1[0:128] + W1[256:384] + W1[384:512]
//  [16384,32768)  Wb  [n][k]  = 3*W1[128:256]
//  [32768,49152)  W2p [n][k]
//  [49152,65536)  W3p [n][k]
//  [65536,67584)  Wop [16][128] (cols 6..15 zero)
//  [67584,67712)  b1 as f16 (128)
//  [67712, +25.6M) uv [atom][256] f16: u = h@Wa (0:128), v = h@Wb (128:256)
#define PB1 67584
#define UV_OFF 67712
#define WS_NEED (2ull * (UV_OFF + (unsigned long long)N_ATOMS * 256))

__global__ __launch_bounds__(256) void prep_kernel(
    const float* __restrict__ W1, const float* __restrict__ W2,
    const float* __restrict__ W3, const float* __restrict__ Wo,
    const float* __restrict__ b1, unsigned short* __restrict__ P) {
  int t = blockIdx.x * 256 + threadIdx.x;  // grid 265 blocks = 67840 threads
  if (t >= UV_OFF) return;
  float v;
  if (t < 16384) {
    int n = t >> 7, k = t & 127;
    v = W1[k * 128 + n] + W1[(k + 256) * 128 + n] + W1[(k + 384) * 128 + n];
  } else if (t < 32768) {
    int i = t - 16384; int n = i >> 7, k = i & 127;
    v = 3.0f * W1[(k + 128) * 128 + n];
  } else if (t < 49152) {
    int i = t - 32768; int n = i >> 7, k = i & 127;
    v = W2[k * 128 + n];
  } else if (t < 65536) {
    int i = t - 49152; int n = i >> 7, k = i & 127;
    v = W3[k * 128 + n];
  } else if (t < PB1) {
    int i = t - 65536; int n = i >> 7, k = i & 127;
    v = (n < 6) ? Wo[k * 6 + n] : 0.0f;
  } else {
    v = b1[t - PB1];
  }
  P[t] = f2h(v);
}

// XOR-swizzled row layout, stride 256 B (G4: row-major 256B-stride f16 is a
// 16-way bank conflict on ds_read_b128 without it). Involution applied on the
// writer side (global source offset for gathers / swizzled ds_write for
// weights) and on the read offset (rule #21). XOR of bit 4 preserves 16B
// alignment.
__device__ __forceinline__ int swz_off(int row, int kbyte) {
  return (row * 256 + kbyte) ^ ((row & 7) << 4);
}
__device__ __forceinline__ f16x8 lds_frag(const unsigned short* buf, int row, int k0) {
  return *(const f16x8*)((const char*)buf + swz_off(row, k0 * 2));
}
__device__ __forceinline__ void lds_st1(unsigned short* buf, int row, int col, unsigned short v) {
  *(unsigned short*)((char*)buf + swz_off(row, col * 2)) = v;
}
// Wave-local LDS fence: all lanes share one PC; lgkmcnt(0) drains this wave's
// LDS ops, "memory" clobber stops hipcc moving ds ops across it.
__device__ __forceinline__ void wave_lds_fence() {
  asm volatile("s_waitcnt lgkmcnt(0)" ::: "memory");
}
// Direct global->LDS (no VGPR round-trip). LDS dest = wave-uniform base +
// lane*16; global src is per-lane.
__device__ __forceinline__ void gload16(const void* g, void* l) {
  __builtin_amdgcn_global_load_lds(
      (const __attribute__((address_space(1))) unsigned int*)g,
      (__attribute__((address_space(3))) unsigned int*)l, 16, 0, 0);
}

// ======== atom precompute: uv = [h@Wa | h@Wb], Wab staged in LDS ========
// Weights from LDS (ds_read, lgkmcnt) so the vmcnt queue holds only h-loads
// and uv-stores -> 8 waves/CU genuinely overlap them.
__global__ __launch_bounds__(256, 2) void atom_gemm2(
    const float* __restrict__ h, const unsigned short* __restrict__ P,
    unsigned short* __restrict__ uv) {
  __shared__ __attribute__((aligned(16))) unsigned short Wab[32768];  // 64 KB
  for (int c = threadIdx.x; c < 4096; c += 256) {
    int rw = c >> 4, kc = c & 15;
    *(f16x8*)((char*)Wab + swz_off(rw, kc * 16)) =
        *(const f16x8*)(P + rw * 128 + kc * 8);
  }
  __syncthreads();

  const int lane = threadIdx.x & 63;
  const int wid = threadIdx.x >> 6;
  const int col = lane & 15, hi = lane >> 4;

  for (int at = blockIdx.x * 4 + wid; at < AT_TILES; at += AG_WAVES) {
    const int atom0 = at * 16;
    const float4* ph = (const float4*)(h + (long)(atom0 + col) * 128);
    f16x8 bfr[4];
#pragma unroll
    for (int ks = 0; ks < 4; ++ks) {
      int kf = ks * 32 + hi * 8;  // float index
      float4 v0 = ph[kf / 4], v1 = ph[kf / 4 + 1];
      f16x8 b;
      b[0] = (_Float16)v0.x; b[1] = (_Float16)v0.y; b[2] = (_Float16)v0.z; b[3] = (_Float16)v0.w;
      b[4] = (_Float16)v1.x; b[5] = (_Float16)v1.y; b[6] = (_Float16)v1.z; b[7] = (_Float16)v1.w;
      bfr[ks] = b;
    }
    f32x4 acc[16] = {};
#pragma unroll
    for (int ks = 0; ks < 4; ++ks) {
      int k0 = ks * 32 + hi * 8;
#pragma unroll
      for (int n = 0; n < 16; ++n) {
        f16x8 a = lds_frag(Wab, n * 16 + col, k0);  // A row = feature
        acc[n] = __builtin_amdgcn_mfma_f32_16x16x32_f16(a, bfr[ks], acc[n], 0, 0, 0);
      }
    }
    unsigned short* dst = uv + (long)(atom0 + col) * 256 + hi * 4;
#pragma unroll
    for (int n = 0; n < 16; ++n) {
      uint2 w; w.x = pk2(acc[n][0], acc[n][1]); w.y = pk2(acc[n][2], acc[n][3]);
      *(uint2*)(dst + n * 16) = w;
    }
  }
}

// ===================== janossy7: LDS-weight persistent pipeline =====================
// 1 block (4 waves) per CU, 148 KB LDS: W2/W3/Wo staged once (swizzled);
// per-wave 16 KB gather buf + 4 KB Y. Loop-body VMEM = {16 gathers, 4 idx
// loads, 2 out stores} ONLY -> vmcnt(2) at tile top drains exactly the
// gathers; weight reads are ds ops and never touch the vmcnt queue.
__global__ __launch_bounds__(256, 1) void janossy7(
    const unsigned short* __restrict__ uv, const int* __restrict__ idx0,
    const int* __restrict__ idx1, const int* __restrict__ idx2,
    const int* __restrict__ idx3, const float* __restrict__ b2,
    const float* __restrict__ b3, const float* __restrict__ bo,
    const unsigned short* __restrict__ P, float* __restrict__ out) {
  __shared__ __attribute__((aligned(16))) unsigned short Wl2[16384];  // 32 KB
  __shared__ __attribute__((aligned(16))) unsigned short Wl3[16384];  // 32 KB
  __shared__ __attribute__((aligned(16))) unsigned short Wol[2048];   //  4 KB
  __shared__ __attribute__((aligned(16))) unsigned short Gb[4][8192]; // 64 KB
  __shared__ __attribute__((aligned(16))) unsigned short Yb[4][2048]; // 16 KB

  // ---- stage weights (once per block), swizzled writes ----
  for (int c = threadIdx.x; c < 2048; c += 256) {
    int rw = c >> 4, kc = c & 15;
    *(f16x8*)((char*)Wl2 + swz_off(rw, kc * 16)) =
        *(const f16x8*)(P + 32768 + rw * 128 + kc * 8);
    *(f16x8*)((char*)Wl3 + swz_off(rw, kc * 16)) =
        *(const f16x8*)(P + 49152 + rw * 128 + kc * 8);
  }
  {
    int c = threadIdx.x;  // 256 chunks exactly
    int rw = c >> 4, kc = c & 15;
    *(f16x8*)((char*)Wol + swz_off(rw, kc * 16)) =
        *(const f16x8*)(P + 65536 + rw * 128 + kc * 8);
  }
  __syncthreads();  // only block-wide barrier; waves free-run afterwards

  const int lane = threadIdx.x & 63;
  const int wid = threadIdx.x >> 6;
  const int row = lane & 15, hi = lane >> 4;
  unsigned short* G = Gb[wid];
  unsigned short* Y = Yb[wid];
  const char* uvB = (const char*)uv;
  const unsigned int c16 = (unsigned int)(row * 16);

  // ---- loop-invariant register preloads (keep loop-body VMEM minimal) ----
  f16x8 b1f[4];
  float b2r[8], b3r[8];
#pragma unroll
  for (int ks = 0; ks < 4; ++ks) b1f[ks] = *(const f16x8*)(P + PB1 + ks * 32 + hi * 8);
#pragma unroll
  for (int n = 0; n < 8; ++n) { b2r[n] = b2[n * 16 + row]; b3r[n] = b3[n * 16 + row]; }
  const float bov = (row < 6) ? bo[row] : 0.0f;

  int jj[4][4];  // next-tile indices (statically indexed)
  auto ld_idx = [&](int tt) {
#pragma unroll
    for (int g = 0; g < 4; ++g) {
      int rr = tt * 16 + g * 4 + hi;
      jj[g][0] = idx0[rr]; jj[g][1] = idx1[rr];
      jj[g][2] = idx2[rr]; jj[g][3] = idx3[rr];
    }
  };
  // 16 gathers; source offset pre-XOR-swizzled, LDS dest linear (base+lane*16).
  auto issue_g = [&]() {
#pragma unroll
    for (int g = 0; g < 4; ++g) {
      const int grow = g * 4 + hi;
      const unsigned int colb = c16 ^ (unsigned int)((grow & 7) << 4);
      char* base = (char*)G + g * 1024;
      gload16(uvB + (long)jj[g][0] * 512 + colb,       base);           // u[idx0]
      gload16(uvB + (long)jj[g][2] * 512 + colb,       base + 4096);    // u[idx2]
      gload16(uvB + (long)jj[g][3] * 512 + colb,       base + 8192);    // u[idx3]
      gload16(uvB + (long)jj[g][1] * 512 + 256 + colb, base + 12288);   // v[idx1]
    }
  };

  int t = blockIdx.x * 4 + wid;  // < 1024 <= NT16: all waves start valid
  ld_idx(t);
  asm volatile("s_waitcnt vmcnt(0)" ::: "memory");  // jj ready
  issue_g();
  int tn = t + J7_WAVES;
  if (tn < NT16) ld_idx(tn);

  for (;;) {
    const bool hn = (tn < NT16);  // wave-uniform
    // gathers are the 16 oldest VMEM ops; allow the 2 youngest (out stores)
    // to linger.
    asm volatile("s_waitcnt vmcnt(2)" ::: "memory");
    __builtin_amdgcn_sched_barrier(0);

    // ---- consume: x = relu(u0+u2+u3+v1+b1), packed f16 A-frags ----
    f16x8 x[4];
#pragma unroll
    for (int ks = 0; ks < 4; ++ks) {
      int k0 = ks * 32 + hi * 8;
      f16x8 s = lds_frag(G, row, k0) + lds_frag(G + 2048, row, k0) +
                lds_frag(G + 4096, row, k0) + lds_frag(G + 6144, row, k0) + b1f[ks];
      f16x8 z = {};
      x[ks] = __builtin_elementwise_max(s, z);
    }
    wave_lds_fence();  // G reads retired -> buffer reusable

    // ---- reissue gather buffer for t+1; prefetch idx two ahead ----
    if (hn) {
      issue_g();
      int t2 = tn + J7_WAVES;
      if (t2 < NT16) ld_idx(t2);
    }

    // ---- layer 2 (A regs, B from LDS) ----
    f32x4 acc[8] = {};
#pragma unroll
    for (int ks = 0; ks < 4; ++ks) {
      int k0 = ks * 32 + hi * 8;
#pragma unroll
      for (int n = 0; n < 8; ++n) {
        f16x8 b = lds_frag(Wl2, n * 16 + row, k0);
        acc[n] = __builtin_amdgcn_mfma_f32_16x16x32_f16(x[ks], b, acc[n], 0, 0, 0);
      }
    }
#pragma unroll
    for (int n = 0; n < 8; ++n) {
      int col = n * 16 + row;
#pragma unroll
      for (int r = 0; r < 4; ++r) {
        float v = fmaxf(acc[n][r] + b2r[n], 0.0f);
        lds_st1(Y, hi * 4 + r, col, f2h(v));
      }
    }
    wave_lds_fence();

    // ---- layer 3 ----
    f32x4 acc3[8] = {};
#pragma unroll
    for (int ks = 0; ks < 4; ++ks) {
      int k0 = ks * 32 + hi * 8;
      f16x8 a = lds_frag(Y, row, k0);
#pragma unroll
      for (int n = 0; n < 8; ++n) {
        f16x8 b = lds_frag(Wl3, n * 16 + row, k0);
        acc3[n] = __builtin_amdgcn_mfma_f32_16x16x32_f16(a, b, acc3[n], 0, 0, 0);
      }
    }
    wave_lds_fence();  // Y reads done before overwrite
#pragma unroll
    for (int n = 0; n < 8; ++n) {
      int col = n * 16 + row;
#pragma unroll
      for (int r = 0; r < 4; ++r) {
        float v = fmaxf(acc3[n][r] + b3r[n], 0.0f);
        lds_st1(Y, hi * 4 + r, col, f2h(v));
      }
    }
    wave_lds_fence();

    // ---- head + coalesced store ----
    {
      f32x4 acch = {0.f, 0.f, 0.f, 0.f};
#pragma unroll
      for (int ks = 0; ks < 4; ++ks) {
        int k0 = ks * 32 + hi * 8;
        f16x8 a = lds_frag(Y, row, k0);
        f16x8 b = lds_frag(Wol, row, k0);
        acch = __builtin_amdgcn_mfma_f32_16x16x32_f16(a, b, acch, 0, 0, 0);
      }
      wave_lds_fence();  // Y A-frag reads done before OS overwrite
      float* OS = (float*)Y;  // 384 B staging
      if (row < 6) {
#pragma unroll
        for (int r = 0; r < 4; ++r) OS[(hi * 4 + r) * 6 + row] = acch[r] + bov;
      }
      wave_lds_fence();
      if (lane < 48) {
        float2 v = ((const float2*)OS)[lane];
        *(float2*)(out + (long)t * 96 + lane * 2) = v;
      }
    }

    if (!hn) break;
    t = tn;
    tn = t + J7_WAVES;
  }
}

// ===================== fallback path (R1, needs only 136 KB ws) =====================

__device__ __forceinline__ void lds_st4(unsigned short* buf, int row, int k0,
                                        float a, float b, float c, float d) {
  uint2 u; u.x = pk2(a, b); u.y = pk2(c, d);
  *(uint2*)((char*)buf + swz_off(row, k0 * 2)) = u;
}

template <bool DUAL>
__device__ __forceinline__ void mlp_layer(
    const unsigned short* A1, const unsigned short* __restrict__ B1,
    const unsigned short* A2, const unsigned short* __restrict__ B2,
    const float* __restrict__ bias, unsigned short* Obuf, int lane, int wr, int wc) {
  f32x4 acc[2][4] = {};
#pragma unroll
  for (int ks = 0; ks < 4; ++ks) {
    int k0 = ks * 32 + (lane >> 4) * 8;
    f16x8 a0 = lds_frag(A1, wr * 32 + (lane & 15), k0);
    f16x8 a1 = lds_frag(A1, wr * 32 + 16 + (lane & 15), k0);
#pragma unroll
    for (int n = 0; n < 4; ++n) {
      int col = wc * 64 + n * 16 + (lane & 15);
      f16x8 b = *(const f16x8*)(B1 + col * 128 + k0);
      acc[0][n] = __builtin_amdgcn_mfma_f32_16x16x32_f16(a0, b, acc[0][n], 0, 0, 0);
      acc[1][n] = __builtin_amdgcn_mfma_f32_16x16x32_f16(a1, b, acc[1][n], 0, 0, 0);
    }
  }
  if constexpr (DUAL) {
#pragma unroll
    for (int ks = 0; ks < 4; ++ks) {
      int k0 = ks * 32 + (lane >> 4) * 8;
      f16x8 a0 = lds_frag(A2, wr * 32 + (lane & 15), k0);
      f16x8 a1 = lds_frag(A2, wr * 32 + 16 + (lane & 15), k0);
#pragma unroll
      for (int n = 0; n < 4; ++n) {
        int col = wc * 64 + n * 16 + (lane & 15);
        f16x8 b = *(const f16x8*)(B2 + col * 128 + k0);
        acc[0][n] = __builtin_amdgcn_mfma_f32_16x16x32_f16(a0, b, acc[0][n], 0, 0, 0);
        acc[1][n] = __builtin_amdgcn_mfma_f32_16x16x32_f16(a1, b, acc[1][n], 0, 0, 0);
      }
    }
  }
#pragma unroll
  for (int n = 0; n < 4; ++n) {
    int col = wc * 64 + n * 16 + (lane & 15);
    float bn = bias[col];
#pragma unroll
    for (int m = 0; m < 2; ++m) {
#pragma unroll
      for (int r = 0; r < 4; ++r) {
        float v = fmaxf(acc[m][n][r] + bn, 0.0f);
        lds_st1(Obuf, wr * 32 + m * 16 + (lane >> 4) * 4 + r, col, f2h(v));
      }
    }
  }
}

__global__ __launch_bounds__(256) void janossy_kernel(
    const float* __restrict__ h, const int* __restrict__ idx0,
    const int* __restrict__ idx1, const int* __restrict__ idx2,
    const int* __restrict__ idx3, const float* __restrict__ b1,
    const float* __restrict__ b2, const float* __restrict__ b3,
    const float* __restrict__ bo, const unsigned short* __restrict__ P,
    float* __restrict__ out) {
  __shared__ __attribute__((aligned(16))) unsigned short sA[64 * 128];
  __shared__ __attribute__((aligned(16))) unsigned short tA[64 * 128];
  __shared__ __attribute__((aligned(16))) unsigned short xA[64 * 128];
  const int tid = threadIdx.x;
  const int lane = tid & 63;
  const int wid = tid >> 6;
  const int wr = wid & 1, wc = wid >> 1;
  const int blk = blockIdx.x;
  {
    int row = tid >> 2, q = tid & 3;
    int rg = blk * 64 + row;
    if (rg < N_IMP) {
      const float4* p0 = (const float4*)h + (long)idx0[rg] * 32 + q * 8;
      const float4* p1 = (const float4*)h + (long)idx1[rg] * 32 + q * 8;
      const float4* p2 = (const float4*)h + (long)idx2[rg] * 32 + q * 8;
      const float4* p3 = (const float4*)h + (long)idx3[rg] * 32 + q * 8;
#pragma unroll
      for (int c = 0; c < 8; ++c) {
        float4 v0 = p0[c], v1 = p1[c], v2 = p2[c], v3 = p3[c];
        int k0 = q * 32 + c * 4;
        lds_st4(sA, row, k0, v0.x + v2.x + v3.x, v0.y + v2.y + v3.y,
                v0.z + v2.z + v3.z, v0.w + v2.w + v3.w);
        lds_st4(tA, row, k0, v1.x, v1.y, v1.z, v1.w);
      }
    } else {
#pragma unroll
      for (int c = 0; c < 8; ++c) {
        int k0 = q * 32 + c * 4;
        lds_st4(sA, row, k0, 0.f, 0.f, 0.f, 0.f);
        lds_st4(tA, row, k0, 0.f, 0.f, 0.f, 0.f);
      }
    }
  }
  __syncthreads();
  mlp_layer<true>(sA, P, tA, P + 16384, b1, xA, lane, wr, wc);
  __syncthreads();
  mlp_layer<false>(xA, P + 32768, nullptr, nullptr, b2, sA, lane, wr, wc);
  __syncthreads();
  mlp_layer<false>(sA, P + 49152, nullptr, nullptr, b3, tA, lane, wr, wc);
  __syncthreads();
  {
    f32x4 acc = {0.f, 0.f, 0.f, 0.f};
#pragma unroll
    for (int ks = 0; ks < 4; ++ks) {
      int k0 = ks * 32 + (lane >> 4) * 8;
      f16x8 a = lds_frag(tA, wid * 16 + (lane & 15), k0);
      f16x8 b = *(const f16x8*)(P + 65536 + (lane & 15) * 128 + k0);
      acc = __builtin_amdgcn_mfma_f32_16x16x32_f16(a, b, acc, 0, 0, 0);
    }
    int col = lane & 15;
    if (col < 6) {
      float bov = bo[col];
#pragma unroll
      for (int r = 0; r < 4; ++r) {
        int rg = blk * 64 + wid * 16 + (lane >> 4) * 4 + r;
        if (rg < N_IMP) out[rg * 6 + col] = acc[r] + bov;
      }
    }
  }
}

extern "C" void kernel_launch(void* const* d_in, const int* in_sizes, int n_in,
                              void* d_out, int out_size, void* d_ws, size_t ws_size,
                              hipStream_t stream) {
  const float* h   = (const float*)d_in[0];
  const int* idx0  = (const int*)d_in[1];
  const int* idx1  = (const int*)d_in[2];
  const int* idx2  = (const int*)d_in[3];
  const int* idx3  = (const int*)d_in[4];
  const float* W1  = (const float*)d_in[5];
  const float* b1  = (const float*)d_in[6];
  const float* W2  = (const float*)d_in[7];
  const float* b2  = (const float*)d_in[8];
  const float* W3  = (const float*)d_in[9];
  const float* b3  = (const float*)d_in[10];
  const float* Wo  = (const float*)d_in[11];
  const float* bo  = (const float*)d_in[12];
  float* out = (float*)d_out;
  unsigned short* P = (unsigned short*)d_ws;

  prep_kernel<<<dim3(265), dim3(256), 0, stream>>>(W1, W2, W3, Wo, b1, P);
  if (ws_size >= WS_NEED) {
    unsigned short* uv = P + UV_OFF;
    atom_gemm2<<<dim3(AG_BLOCKS), dim3(256), 0, stream>>>(h, P, uv);
    janossy7<<<dim3(J7_BLOCKS), dim3(256), 0, stream>>>(
        uv, idx0, idx1, idx2, idx3, b2, b3, bo, P, out);
  } else {
    janossy_kernel<<<dim3((N_IMP + 63) / 64), dim3(256), 0, stream>>>(
        h, idx0, idx1, idx2, idx3, b1, b2, b3, bo, P, out);
  }
}